// Round 1
// baseline (390.213 us; speedup 1.0000x reference)
//
#include <hip/hip_runtime.h>
#include <hip/hip_bf16.h>

#define NBOX  380
#define NLOCS 85
#define NINST 340   // B(4) * NLOCS(85)

// box index -> location index (from _recon_indices structure)
__device__ __forceinline__ int loc_of_box(int n) {
    if (n < 256) return n >> 2;               // fm=8, 4 boxes/loc
    if (n < 352) return 64 + (n - 256) / 6;   // fm=4, 6 boxes/loc
    if (n < 376) return 80 + (n - 352) / 6;   // fm=2, 6 boxes/loc
    return 84;                                // fm=1, 4 boxes/loc
}

// Per-batch softmax over depths + per-box affine sampling params.
// px = fma(w_pixel, sxs, oxs), py = fma(h_pixel, sys, oys)
__global__ void box_params_k(const float* __restrict__ zwhere,
                             const int* __restrict__ zpresent,
                             const float* __restrict__ zdepth,
                             float* __restrict__ wgt, float* __restrict__ sxs,
                             float* __restrict__ oxs, float* __restrict__ sys,
                             float* __restrict__ oys, int* __restrict__ binst)
{
    int b = blockIdx.x;
    int tid = threadIdx.x;            // 128 threads
    __shared__ float sd[NBOX];
    __shared__ float red[128];

    for (int n = tid; n < NBOX; n += 128) {
        int loc = loc_of_box(n);
        float d = (zpresent[b * NBOX + n] == 1) ? zdepth[b * NLOCS + loc] : -1000.0f;
        sd[n] = d;
    }
    __syncthreads();

    float m = -1e30f;
    for (int n = tid; n < NBOX; n += 128) m = fmaxf(m, sd[n]);
    red[tid] = m; __syncthreads();
    for (int s = 64; s > 0; s >>= 1) {
        if (tid < s) red[tid] = fmaxf(red[tid], red[tid + s]);
        __syncthreads();
    }
    m = red[0]; __syncthreads();

    float sum = 0.0f;
    for (int n = tid; n < NBOX; n += 128) sum += expf(sd[n] - m);
    red[tid] = sum; __syncthreads();
    for (int s = 64; s > 0; s >>= 1) {
        if (tid < s) red[tid] += red[tid + s];
        __syncthreads();
    }
    float inv = 1.0f / red[0];

    for (int n = tid; n < NBOX; n += 128) {
        int g = b * NBOX + n;
        wgt[g] = expf(sd[n] - m) * inv;   // exp(-1000-m) underflows to 0 exactly (matches np)
        float cx = zwhere[g * 4 + 0], cy = zwhere[g * 4 + 1];
        float w  = zwhere[g * 4 + 2], h  = zwhere[g * 4 + 3];
        float isx = 1.0f / fmaxf(w, 1e-5f);
        float isy = 1.0f / fmaxf(h, 1e-5f);
        // px = ((out_x - (2cx-1))/sx + 1)*31.5, out_x = -1 + 2*w_pix/127
        sxs[g] = isx * (63.0f / 127.0f);
        oxs[g] = 31.5f * (1.0f - 2.0f * cx * isx);
        sys[g] = isy * (63.0f / 127.0f);
        oys[g] = 31.5f * (1.0f - 2.0f * cy * isy);
        binst[g] = b * NLOCS + loc_of_box(n);
    }
}

// 2x2 stride-2 VALID conv_transpose, HWC activation layout.
// out[(oy*sout+ox)*cout+co] = act( b[co] + sum_ci x[(i*sin+j)*cin+ci] * w[1-di][1-dj][ci][co] )
__global__ void deconv2x2_k(const float* __restrict__ in, const float* __restrict__ wt,
                            const float* __restrict__ bias, float* __restrict__ out,
                            int cin, int cout, int sin, int act, int total)
{
    int inst = blockIdx.x;
    const float* x = in + (size_t)inst * cin * sin * sin;
    float* y = out + (size_t)inst * (size_t)(cout * 4 * sin) * sin;
    int sout = sin * 2;
    int base = blockIdx.y * 2048;
    int end = min(total, base + 2048);
    for (int o = base + (int)threadIdx.x; o < end; o += 256) {
        int co = o % cout;
        int p = o / cout;
        int ox = p % sout, oy = p / sout;
        int i = oy >> 1, di = oy & 1, j = ox >> 1, dj = ox & 1;
        const float* wp = wt + (size_t)(((1 - di) * 2 + (1 - dj)) * cin) * cout + co;
        const float* xp = x + (size_t)(i * sin + j) * cin;
        float acc = bias[co];
        #pragma unroll 4
        for (int ci = 0; ci < cin; ++ci)
            acc = fmaf(xp[ci], wp[(size_t)ci * cout], acc);
        acc = act ? (1.0f / (1.0f + expf(-acc))) : fmaxf(acc, 0.0f);
        y[o] = acc;
    }
}

// Fused STN bilinear sample + softmax-weighted composite over all boxes.
__global__ __launch_bounds__(256) void composite_k(
    const float* __restrict__ dec, const float* __restrict__ wgt,
    const float* __restrict__ sxs, const float* __restrict__ oxs,
    const float* __restrict__ sys, const float* __restrict__ oys,
    const int* __restrict__ binst, float* __restrict__ out)
{
    int b = blockIdx.y;
    int pix = blockIdx.x * 256 + threadIdx.x;   // 0..16383
    int h = pix >> 7, w = pix & 127;

    __shared__ float s_w[NBOX], s_sx[NBOX], s_ox[NBOX], s_sy[NBOX], s_oy[NBOX];
    __shared__ int s_i[NBOX];
    for (int n = threadIdx.x; n < NBOX; n += 256) {
        int g = b * NBOX + n;
        s_w[n] = wgt[g]; s_sx[n] = sxs[g]; s_ox[n] = oxs[g];
        s_sy[n] = sys[g]; s_oy[n] = oys[g]; s_i[n] = binst[g];
    }
    __syncthreads();

    float fw = (float)w, fh = (float)h;
    float a0 = 0.f, a1 = 0.f, a2 = 0.f;
    for (int n = 0; n < NBOX; ++n) {
        float wg = s_w[n];
        if (wg == 0.0f) continue;               // absent box: weight underflowed to 0 (uniform branch)
        float px = fmaf(fw, s_sx[n], s_ox[n]);
        float py = fmaf(fh, s_sy[n], s_oy[n]);
        float x0 = floorf(px), y0 = floorf(py);
        if (x0 < -1.0f || x0 > 63.0f || y0 < -1.0f || y0 > 63.0f) continue;
        float wx = px - x0, wy = py - y0;
        int ix = (int)x0, iy = (int)y0;
        int x0c = max(ix, 0), x1c = min(ix + 1, 63);
        int y0c = max(iy, 0), y1c = min(iy + 1, 63);
        float m00 = (ix >= 0 && iy >= 0) ? 1.f : 0.f;
        float m01 = (ix + 1 <= 63 && iy >= 0) ? 1.f : 0.f;
        float m10 = (ix >= 0 && iy + 1 <= 63) ? 1.f : 0.f;
        float m11 = (ix + 1 <= 63 && iy + 1 <= 63) ? 1.f : 0.f;
        float w00 = (1.f - wy) * (1.f - wx) * m00;
        float w01 = (1.f - wy) * wx * m01;
        float w10 = wy * (1.f - wx) * m10;
        float w11 = wy * wx * m11;
        const float* img = dec + (size_t)s_i[n] * 12288;   // (64,64,3) HWC
        int b00 = (y0c * 64 + x0c) * 3, b01 = (y0c * 64 + x1c) * 3;
        int b10 = (y1c * 64 + x0c) * 3, b11 = (y1c * 64 + x1c) * 3;
        a0 += wg * (w00 * img[b00]   + w01 * img[b01]   + w10 * img[b10]   + w11 * img[b11]);
        a1 += wg * (w00 * img[b00+1] + w01 * img[b01+1] + w10 * img[b10+1] + w11 * img[b11+1]);
        a2 += wg * (w00 * img[b00+2] + w01 * img[b01+2] + w10 * img[b10+2] + w11 * img[b11+2]);
    }
    out[((b * 3 + 0) * 128 + h) * 128 + w] = a0;
    out[((b * 3 + 1) * 128 + h) * 128 + w] = a1;
    out[((b * 3 + 2) * 128 + h) * 128 + w] = a2;
}

extern "C" void kernel_launch(void* const* d_in, const int* in_sizes, int n_in,
                              void* d_out, int out_size, void* d_ws, size_t ws_size,
                              hipStream_t stream)
{
    const float* z_what   = (const float*)d_in[0];   // (4,85,64)
    const float* z_where  = (const float*)d_in[1];   // (4,380,4)
    const int*   z_present= (const int*)  d_in[2];   // (4,380,1)
    const float* z_depth  = (const float*)d_in[3];   // (4,85,1)
    const float* W[6]; const float* Bs[6];
    for (int i = 0; i < 6; ++i) {
        W[i]  = (const float*)d_in[4 + 2 * i];
        Bs[i] = (const float*)d_in[5 + 2 * i];
    }

    // workspace layout (bytes):
    //   A: 0            .. 22,282,240   (max intermediate: L4 out, 340*16384 f32)
    //   B: 22,282,240   .. 38,993,920   (max: decoded 340*12288 f32)
    //   P: 38,993,920   .. +36,480      (box params: 5 f32 + 1 i32 arrays of 1520)
    char* ws = (char*)d_ws;
    float* A    = (float*)ws;
    float* Bbuf = (float*)(ws + 22282240);
    float* P    = (float*)(ws + 38993920);
    float* wgt = P, *sxs = P + 1520, *oxs = P + 2 * 1520, *sys = P + 3 * 1520, *oys = P + 4 * 1520;
    int* binst = (int*)(P + 5 * 1520);

    box_params_k<<<dim3(4), dim3(128), 0, stream>>>(z_where, z_present, z_depth,
                                                    wgt, sxs, oxs, sys, oys, binst);

    struct Layer { const float* in; float* out; int cin, cout, sin, act; };
    Layer L[6] = {
        { z_what, A,    64, 256,  1, 0 },
        { A,      Bbuf, 256, 128, 2, 0 },
        { Bbuf,   A,    128, 64,  4, 0 },
        { A,      Bbuf, 64,  32,  8, 0 },
        { Bbuf,   A,    32,  16, 16, 0 },
        { A,      Bbuf, 16,   3, 32, 1 },   // sigmoid
    };
    for (int l = 0; l < 6; ++l) {
        int total = L[l].cout * 4 * L[l].sin * L[l].sin;
        int nby = (total + 2047) / 2048;
        deconv2x2_k<<<dim3(NINST, nby), dim3(256), 0, stream>>>(
            L[l].in, W[l], Bs[l], L[l].out, L[l].cin, L[l].cout, L[l].sin, L[l].act, total);
    }

    composite_k<<<dim3(64, 4), dim3(256), 0, stream>>>(Bbuf, wgt, sxs, oxs, sys, oys,
                                                       binst, (float*)d_out);
}

// Round 2
// 269.977 us; speedup vs baseline: 1.4454x; 1.4454x over previous
//
#include <hip/hip_runtime.h>
#include <hip/hip_bf16.h>

#define NBOX  380
#define NLOCS 85
#define NINST 340   // B(4) * NLOCS(85)

// box index -> location index (from _recon_indices structure)
__device__ __forceinline__ int loc_of_box(int n) {
    if (n < 256) return n >> 2;               // fm=8, 4 boxes/loc
    if (n < 352) return 64 + (n - 256) / 6;   // fm=4, 6 boxes/loc
    if (n < 376) return 80 + (n - 352) / 6;   // fm=2, 6 boxes/loc
    return 84;                                // fm=1, 4 boxes/loc
}

// Per-batch softmax over depths + per-box affine sampling params.
__global__ void box_params_k(const float* __restrict__ zwhere,
                             const int* __restrict__ zpresent,
                             const float* __restrict__ zdepth,
                             float* __restrict__ wgt, float* __restrict__ sxs,
                             float* __restrict__ oxs, float* __restrict__ sys,
                             float* __restrict__ oys, int* __restrict__ binst)
{
    int b = blockIdx.x;
    int tid = threadIdx.x;            // 128 threads
    __shared__ float sd[NBOX];
    __shared__ float red[128];

    for (int n = tid; n < NBOX; n += 128) {
        int loc = loc_of_box(n);
        float d = (zpresent[b * NBOX + n] == 1) ? zdepth[b * NLOCS + loc] : -1000.0f;
        sd[n] = d;
    }
    __syncthreads();

    float m = -1e30f;
    for (int n = tid; n < NBOX; n += 128) m = fmaxf(m, sd[n]);
    red[tid] = m; __syncthreads();
    for (int s = 64; s > 0; s >>= 1) {
        if (tid < s) red[tid] = fmaxf(red[tid], red[tid + s]);
        __syncthreads();
    }
    m = red[0]; __syncthreads();

    float sum = 0.0f;
    for (int n = tid; n < NBOX; n += 128) sum += expf(sd[n] - m);
    red[tid] = sum; __syncthreads();
    for (int s = 64; s > 0; s >>= 1) {
        if (tid < s) red[tid] += red[tid + s];
        __syncthreads();
    }
    float inv = 1.0f / red[0];

    for (int n = tid; n < NBOX; n += 128) {
        int g = b * NBOX + n;
        wgt[g] = expf(sd[n] - m) * inv;   // exp(-1000-m) underflows to 0 exactly (matches np)
        float cx = zwhere[g * 4 + 0], cy = zwhere[g * 4 + 1];
        float w  = zwhere[g * 4 + 2], h  = zwhere[g * 4 + 3];
        float isx = 1.0f / fmaxf(w, 1e-5f);
        float isy = 1.0f / fmaxf(h, 1e-5f);
        sxs[g] = isx * (63.0f / 127.0f);
        oxs[g] = 31.5f * (1.0f - 2.0f * cx * isx);
        sys[g] = isy * (63.0f / 127.0f);
        oys[g] = 31.5f * (1.0f - 2.0f * cy * isy);
        binst[g] = b * NLOCS + loc_of_box(n);
    }
}

// Deconv layer as SGEMM: Y[M, 4*cout] = X[M,K] . W4[K, 4*cout]
//   X is the HWC input, rows m = inst*sin*sin + i*sin + j (contiguous).
//   W4[k][t*cout+co] = w[3-t][k][co]   (tap flip: out[2i+di,2j+dj] uses w[1-di,1-dj])
//   Output scattered to HWC: y[inst][(2i+di)*sout + 2j+dj][co], bias+act fused.
// Block tile 64 x (16*TN), 256 threads (16x16), 4xTN micro-tile, BK=32.
template<int TN>
__global__ __launch_bounds__(256) void deconv_gemm_k(
    const float* __restrict__ X, const float* __restrict__ Wt,
    const float* __restrict__ bias, float* __restrict__ Y,
    int M, int K, int cout, int sin, int act)
{
    constexpr int BN = 16 * TN;
    const int N4 = 4 * cout;
    const int S2 = sin * sin;
    const int sout = 2 * sin;

    __shared__ float Xs[64][33];
    __shared__ float Ws[32][BN];

    const int tid = threadIdx.x;
    const int tx = tid & 15, ty = tid >> 4;
    const int mbase = blockIdx.x * 64;
    const int nbase = blockIdx.y * BN;

    float acc[4][TN];
    #pragma unroll
    for (int r = 0; r < 4; ++r)
        #pragma unroll
        for (int c = 0; c < TN; ++c) acc[r][c] = 0.f;

    const int KC = (K + 31) >> 5;
    for (int kc = 0; kc < KC; ++kc) {
        const int k0 = kc << 5;
        // stage X tile (64 x 32), coalesced along K
        #pragma unroll
        for (int idx = tid; idx < 64 * 32; idx += 256) {
            int mm = idx >> 5, kk = idx & 31;
            int row = mbase + mm, k = k0 + kk;
            Xs[mm][kk] = (row < M && k < K) ? X[(size_t)row * K + k] : 0.f;
        }
        // stage W tile (32 x BN), coalesced along co
        for (int idx = tid; idx < 32 * BN; idx += 256) {
            int kk = idx / BN, nn = idx - kk * BN;
            int c = nbase + nn, k = k0 + kk;
            float v = 0.f;
            if (c < N4 && k < K) {
                int t = c / cout, co = c - t * cout;
                v = Wt[(size_t)(3 - t) * K * cout + (size_t)k * cout + co];
            }
            Ws[kk][nn] = v;
        }
        __syncthreads();

        #pragma unroll
        for (int kk = 0; kk < 32; ++kk) {
            float a[4], b[TN];
            #pragma unroll
            for (int r = 0; r < 4; ++r) a[r] = Xs[ty + 16 * r][kk];
            #pragma unroll
            for (int c = 0; c < TN; ++c) b[c] = Ws[kk][tx + 16 * c];
            #pragma unroll
            for (int r = 0; r < 4; ++r)
                #pragma unroll
                for (int c = 0; c < TN; ++c)
                    acc[r][c] = fmaf(a[r], b[c], acc[r][c]);
        }
        __syncthreads();
    }

    // epilogue: bias + activation + HWC scatter
    #pragma unroll
    for (int r = 0; r < 4; ++r) {
        int row = mbase + ty + 16 * r;
        if (row >= M) continue;
        int inst = row / S2, p = row - inst * S2;
        int i = p / sin, j = p - i * sin;
        size_t ybase = (size_t)inst * S2 * 4 * cout;
        #pragma unroll
        for (int c = 0; c < TN; ++c) {
            int col = nbase + tx + 16 * c;
            if (col >= N4) continue;
            int t = col / cout, co = col - t * cout;
            int oy = 2 * i + (t >> 1), ox = 2 * j + (t & 1);
            float v = acc[r][c] + bias[co];
            v = act ? (1.0f / (1.0f + expf(-v))) : fmaxf(v, 0.f);
            Y[ybase + (size_t)(oy * sout + ox) * cout + co] = v;
        }
    }
}

// Fused STN bilinear sample + softmax-weighted composite over all boxes.
__global__ __launch_bounds__(256) void composite_k(
    const float* __restrict__ dec, const float* __restrict__ wgt,
    const float* __restrict__ sxs, const float* __restrict__ oxs,
    const float* __restrict__ sys, const float* __restrict__ oys,
    const int* __restrict__ binst, float* __restrict__ out)
{
    int b = blockIdx.y;
    int pix = blockIdx.x * 256 + threadIdx.x;   // 0..16383
    int h = pix >> 7, w = pix & 127;

    __shared__ float s_w[NBOX], s_sx[NBOX], s_ox[NBOX], s_sy[NBOX], s_oy[NBOX];
    __shared__ int s_i[NBOX];
    for (int n = threadIdx.x; n < NBOX; n += 256) {
        int g = b * NBOX + n;
        s_w[n] = wgt[g]; s_sx[n] = sxs[g]; s_ox[n] = oxs[g];
        s_sy[n] = sys[g]; s_oy[n] = oys[g]; s_i[n] = binst[g];
    }
    __syncthreads();

    float fw = (float)w, fh = (float)h;
    float a0 = 0.f, a1 = 0.f, a2 = 0.f;
    for (int n = 0; n < NBOX; ++n) {
        float wg = s_w[n];
        if (wg == 0.0f) continue;               // absent box: weight underflowed to 0
        float px = fmaf(fw, s_sx[n], s_ox[n]);
        float py = fmaf(fh, s_sy[n], s_oy[n]);
        float x0 = floorf(px), y0 = floorf(py);
        if (x0 < -1.0f || x0 > 63.0f || y0 < -1.0f || y0 > 63.0f) continue;
        float wx = px - x0, wy = py - y0;
        int ix = (int)x0, iy = (int)y0;
        int x0c = max(ix, 0), x1c = min(ix + 1, 63);
        int y0c = max(iy, 0), y1c = min(iy + 1, 63);
        float m00 = (ix >= 0 && iy >= 0) ? 1.f : 0.f;
        float m01 = (ix + 1 <= 63 && iy >= 0) ? 1.f : 0.f;
        float m10 = (ix >= 0 && iy + 1 <= 63) ? 1.f : 0.f;
        float m11 = (ix + 1 <= 63 && iy + 1 <= 63) ? 1.f : 0.f;
        float w00 = (1.f - wy) * (1.f - wx) * m00;
        float w01 = (1.f - wy) * wx * m01;
        float w10 = wy * (1.f - wx) * m10;
        float w11 = wy * wx * m11;
        const float* img = dec + (size_t)s_i[n] * 12288;   // (64,64,3) HWC
        int b00 = (y0c * 64 + x0c) * 3, b01 = (y0c * 64 + x1c) * 3;
        int b10 = (y1c * 64 + x0c) * 3, b11 = (y1c * 64 + x1c) * 3;
        a0 += wg * (w00 * img[b00]   + w01 * img[b01]   + w10 * img[b10]   + w11 * img[b11]);
        a1 += wg * (w00 * img[b00+1] + w01 * img[b01+1] + w10 * img[b10+1] + w11 * img[b11+1]);
        a2 += wg * (w00 * img[b00+2] + w01 * img[b01+2] + w10 * img[b10+2] + w11 * img[b11+2]);
    }
    out[((b * 3 + 0) * 128 + h) * 128 + w] = a0;
    out[((b * 3 + 1) * 128 + h) * 128 + w] = a1;
    out[((b * 3 + 2) * 128 + h) * 128 + w] = a2;
}

extern "C" void kernel_launch(void* const* d_in, const int* in_sizes, int n_in,
                              void* d_out, int out_size, void* d_ws, size_t ws_size,
                              hipStream_t stream)
{
    const float* z_what   = (const float*)d_in[0];   // (4,85,64)
    const float* z_where  = (const float*)d_in[1];   // (4,380,4)
    const int*   z_present= (const int*)  d_in[2];   // (4,380,1)
    const float* z_depth  = (const float*)d_in[3];   // (4,85,1)
    const float* W[6]; const float* Bs[6];
    for (int i = 0; i < 6; ++i) {
        W[i]  = (const float*)d_in[4 + 2 * i];
        Bs[i] = (const float*)d_in[5 + 2 * i];
    }

    // workspace layout (bytes):
    //   A: 0            .. 22,282,240   (max intermediate: L4 out, 340*16384 f32)
    //   B: 22,282,240   .. 38,993,920   (max: decoded 340*12288 f32)
    //   P: 38,993,920   .. +36,480      (box params)
    char* ws = (char*)d_ws;
    float* A    = (float*)ws;
    float* Bbuf = (float*)(ws + 22282240);
    float* P    = (float*)(ws + 38993920);
    float* wgt = P, *sxs = P + 1520, *oxs = P + 2 * 1520, *sys = P + 3 * 1520, *oys = P + 4 * 1520;
    int* binst = (int*)(P + 5 * 1520);

    box_params_k<<<dim3(4), dim3(128), 0, stream>>>(z_where, z_present, z_depth,
                                                    wgt, sxs, oxs, sys, oys, binst);

    struct Layer { const float* in; float* out; int cin, cout, sin, act; };
    Layer L[6] = {
        { z_what, A,    64, 256,  1, 0 },   // M=340    N4=1024
        { A,      Bbuf, 256, 128, 2, 0 },   // M=1360   N4=512
        { Bbuf,   A,    128, 64,  4, 0 },   // M=5440   N4=256
        { A,      Bbuf, 64,  32,  8, 0 },   // M=21760  N4=128
        { Bbuf,   A,    32,  16, 16, 0 },   // M=87040  N4=64
        { A,      Bbuf, 16,   3, 32, 1 },   // M=348160 N4=12, sigmoid
    };
    for (int l = 0; l < 6; ++l) {
        int M = NINST * L[l].sin * L[l].sin;
        int N4 = 4 * L[l].cout;
        int gx = (M + 63) / 64;
        if (L[l].cout >= 16) {
            int gy = (N4 + 63) / 64;
            deconv_gemm_k<4><<<dim3(gx, gy), dim3(256), 0, stream>>>(
                L[l].in, W[l], Bs[l], L[l].out, M, L[l].cin, L[l].cout, L[l].sin, L[l].act);
        } else {
            int gy = (N4 + 15) / 16;
            deconv_gemm_k<1><<<dim3(gx, gy), dim3(256), 0, stream>>>(
                L[l].in, W[l], Bs[l], L[l].out, M, L[l].cin, L[l].cout, L[l].sin, L[l].act);
        }
    }

    composite_k<<<dim3(64, 4), dim3(256), 0, stream>>>(Bbuf, wgt, sxs, oxs, sys, oys,
                                                       binst, (float*)d_out);
}

// Round 3
// 119.978 us; speedup vs baseline: 3.2524x; 2.2502x over previous
//
#include <hip/hip_runtime.h>
#include <hip/hip_bf16.h>

#define NBOX  380
#define NLOCS 85
#define NINST 340   // B(4) * NLOCS(85)
#define NSPLIT 4

// box index -> location index (from _recon_indices structure)
__device__ __forceinline__ int loc_of_box(int n) {
    if (n < 256) return n >> 2;               // fm=8, 4 boxes/loc
    if (n < 352) return 64 + (n - 256) / 6;   // fm=4, 6 boxes/loc
    if (n < 376) return 80 + (n - 352) / 6;   // fm=2, 6 boxes/loc
    return 84;                                // fm=1, 4 boxes/loc
}

// Per-batch softmax over depths + per-box affine sampling params + pixel rect
// + deterministic compaction of contributing (weight>0) boxes.
__global__ void box_params_k(const float* __restrict__ zwhere,
                             const int* __restrict__ zpresent,
                             const float* __restrict__ zdepth,
                             float* __restrict__ wgt, float* __restrict__ sxs,
                             float* __restrict__ oxs, float* __restrict__ sys,
                             float* __restrict__ oys, int* __restrict__ binst,
                             int* __restrict__ rect, int* __restrict__ cidx,
                             int* __restrict__ cnt)
{
    int b = blockIdx.x;
    int tid = threadIdx.x;            // 128 threads
    __shared__ float sd[NBOX];
    __shared__ float red[128];

    for (int n = tid; n < NBOX; n += 128) {
        int loc = loc_of_box(n);
        float d = (zpresent[b * NBOX + n] == 1) ? zdepth[b * NLOCS + loc] : -1000.0f;
        sd[n] = d;
    }
    __syncthreads();

    float m = -1e30f;
    for (int n = tid; n < NBOX; n += 128) m = fmaxf(m, sd[n]);
    red[tid] = m; __syncthreads();
    for (int s = 64; s > 0; s >>= 1) {
        if (tid < s) red[tid] = fmaxf(red[tid], red[tid + s]);
        __syncthreads();
    }
    m = red[0]; __syncthreads();

    float sum = 0.0f;
    for (int n = tid; n < NBOX; n += 128) sum += expf(sd[n] - m);
    red[tid] = sum; __syncthreads();
    for (int s = 64; s > 0; s >>= 1) {
        if (tid < s) red[tid] += red[tid + s];
        __syncthreads();
    }
    float inv = 1.0f / red[0];
    __syncthreads();

    for (int n = tid; n < NBOX; n += 128) {
        int g = b * NBOX + n;
        float wv = expf(sd[n] - m) * inv;   // exp(-1000-m) underflows to 0 exactly
        wgt[g] = wv;
        float cx = zwhere[g * 4 + 0], cy = zwhere[g * 4 + 1];
        float w  = zwhere[g * 4 + 2], h  = zwhere[g * 4 + 3];
        float isx = 1.0f / fmaxf(w, 1e-5f);
        float isy = 1.0f / fmaxf(h, 1e-5f);
        float sxv = isx * (63.0f / 127.0f);
        float oxv = 31.5f * (1.0f - 2.0f * cx * isx);
        float syv = isy * (63.0f / 127.0f);
        float oyv = 31.5f * (1.0f - 2.0f * cy * isy);
        sxs[g] = sxv; oxs[g] = oxv; sys[g] = syv; oys[g] = oyv;
        binst[g] = b * NLOCS + loc_of_box(n);
        // conservative pixel bounding rect: valid sample needs px in [-1, 64)
        int wlo = min(127, max(0, (int)floorf((-1.0f - oxv) / sxv)));
        int whi = max(0, min(127, (int)ceilf((64.0f - oxv) / sxv)));
        int hlo = min(127, max(0, (int)floorf((-1.0f - oyv) / syv)));
        int hhi = max(0, min(127, (int)ceilf((64.0f - oyv) / syv)));
        rect[g] = wlo | (whi << 8) | (hlo << 16) | (hhi << 24);
        sd[n] = wv;   // reuse smem as presence flag for compaction
    }
    __syncthreads();

    if (tid < 64) {   // wave 0: deterministic ascending compaction
        int base = 0;
        for (int c = 0; c < 6; ++c) {
            int n = c * 64 + tid;
            bool p = (n < NBOX) && (sd[n] > 0.0f);
            unsigned long long mask = __ballot(p);
            int pos = __popcll(mask & ((1ull << tid) - 1ull));
            if (p) cidx[b * NBOX + base + pos] = n;
            base += __popcll(mask);
        }
        if (tid == 0) cnt[b] = base;
    }
}

// Deconv layer as SGEMM with LDS-transposed X for vectorized ds_read.
// Y[M, 4*cout] = X[M,K] . W4[K, 4*cout]; W4[k][t*cout+co] = w[3-t][k][co].
// BM = 16*RPT, BN = 64, BK = 32. 256 threads, micro-tile RPT x 4.
// All cout/sin are powers of 2; K is a multiple of 32; N4 a multiple of 64.
template<int RPT>
__global__ __launch_bounds__(256) void deconv_gemm_k(
    const float* __restrict__ X, const float* __restrict__ Wt,
    const float* __restrict__ bias, float* __restrict__ Y,
    int M, int K, int coutsh, int sinsh, int act)
{
    constexpr int BM = 16 * RPT;
    const int cout = 1 << coutsh;
    const int sin = 1 << sinsh;

    __shared__ float Xs[32][BM + 4];   // [k][m], padded
    __shared__ float Ws[32][64];       // [k][n]

    const int tid = threadIdx.x;
    const int tx = tid & 15, ty = tid >> 4;
    const int mbase = blockIdx.x * BM;
    const int nbase = blockIdx.y * 64;

    float acc[RPT][4];
    #pragma unroll
    for (int r = 0; r < RPT; ++r)
        #pragma unroll
        for (int c = 0; c < 4; ++c) acc[r][c] = 0.f;

    const int KC = K >> 5;
    for (int kc = 0; kc < KC; ++kc) {
        const int k0 = kc << 5;
        // stage X transposed (coalesced global reads along K, strided LDS writes)
        if (RPT == 4) {
            int r = tid >> 2, kq = (tid & 3) * 8;
            int row = mbase + r;
            float4 v0 = {0,0,0,0}, v1 = {0,0,0,0};
            if (row < M) {
                const float* p = X + (size_t)row * K + k0 + kq;
                v0 = *(const float4*)p;
                v1 = *(const float4*)(p + 4);
            }
            Xs[kq + 0][r] = v0.x; Xs[kq + 1][r] = v0.y;
            Xs[kq + 2][r] = v0.z; Xs[kq + 3][r] = v0.w;
            Xs[kq + 4][r] = v1.x; Xs[kq + 5][r] = v1.y;
            Xs[kq + 6][r] = v1.z; Xs[kq + 7][r] = v1.w;
        } else {
            int r = tid >> 3, kq = (tid & 7) * 4;
            int row = mbase + r;
            float4 v = {0,0,0,0};
            if (row < M) v = *(const float4*)(X + (size_t)row * K + k0 + kq);
            Xs[kq + 0][r] = v.x; Xs[kq + 1][r] = v.y;
            Xs[kq + 2][r] = v.z; Xs[kq + 3][r] = v.w;
        }
        // stage W (coalesced reads along co, conflict-free LDS writes)
        #pragma unroll
        for (int i2 = 0; i2 < 8; ++i2) {
            int idx = tid + i2 * 256;
            int kk = idx >> 6, nn = idx & 63;
            int col = nbase + nn;
            int t = col >> coutsh, co = col & (cout - 1);
            Ws[kk][nn] = Wt[(size_t)(3 - t) * K * cout + (size_t)(k0 + kk) * cout + co];
        }
        __syncthreads();

        #pragma unroll
        for (int kk = 0; kk < 32; ++kk) {
            float4 bv = *(const float4*)&Ws[kk][tx * 4];
            if (RPT == 4) {
                float4 av = *(const float4*)&Xs[kk][ty * 4];
                acc[0][0] = fmaf(av.x, bv.x, acc[0][0]); acc[0][1] = fmaf(av.x, bv.y, acc[0][1]);
                acc[0][2] = fmaf(av.x, bv.z, acc[0][2]); acc[0][3] = fmaf(av.x, bv.w, acc[0][3]);
                acc[1][0] = fmaf(av.y, bv.x, acc[1][0]); acc[1][1] = fmaf(av.y, bv.y, acc[1][1]);
                acc[1][2] = fmaf(av.y, bv.z, acc[1][2]); acc[1][3] = fmaf(av.y, bv.w, acc[1][3]);
                acc[2][0] = fmaf(av.z, bv.x, acc[2][0]); acc[2][1] = fmaf(av.z, bv.y, acc[2][1]);
                acc[2][2] = fmaf(av.z, bv.z, acc[2][2]); acc[2][3] = fmaf(av.z, bv.w, acc[2][3]);
                acc[3][0] = fmaf(av.w, bv.x, acc[3][0]); acc[3][1] = fmaf(av.w, bv.y, acc[3][1]);
                acc[3][2] = fmaf(av.w, bv.z, acc[3][2]); acc[3][3] = fmaf(av.w, bv.w, acc[3][3]);
            } else {
                float2 av = *(const float2*)&Xs[kk][ty * 2];
                acc[0][0] = fmaf(av.x, bv.x, acc[0][0]); acc[0][1] = fmaf(av.x, bv.y, acc[0][1]);
                acc[0][2] = fmaf(av.x, bv.z, acc[0][2]); acc[0][3] = fmaf(av.x, bv.w, acc[0][3]);
                acc[1][0] = fmaf(av.y, bv.x, acc[1][0]); acc[1][1] = fmaf(av.y, bv.y, acc[1][1]);
                acc[1][2] = fmaf(av.y, bv.z, acc[1][2]); acc[1][3] = fmaf(av.y, bv.w, acc[1][3]);
            }
        }
        __syncthreads();
    }

    // epilogue: bias + activation + HWC scatter
    const int s2sh = 2 * sinsh;
    #pragma unroll
    for (int r = 0; r < RPT; ++r) {
        int row = mbase + ty * RPT + r;
        if (row >= M) continue;
        int inst = row >> s2sh;
        int p = row & ((1 << s2sh) - 1);
        int i = p >> sinsh, j = p & (sin - 1);
        size_t ybase = (size_t)inst << (s2sh + 2 + coutsh);
        #pragma unroll
        for (int c = 0; c < 4; ++c) {
            int col = nbase + tx * 4 + c;
            int t = col >> coutsh, co = col & (cout - 1);
            int oy = 2 * i + (t >> 1), ox = 2 * j + (t & 1);
            float v = acc[r][c] + bias[co];
            v = act ? (1.0f / (1.0f + expf(-v))) : fmaxf(v, 0.f);
            Y[ybase + ((((size_t)oy << (sinsh + 1)) + ox) << coutsh) + co] = v;
        }
    }
}

// Last layer (cin=16, cout=3) dedicated: one thread per output pixel,
// wave-uniform tap -> weights via scalar loads, no LDS.
__global__ __launch_bounds__(256) void deconv_last_k(
    const float* __restrict__ X, const float* __restrict__ Wt,
    const float* __restrict__ bias, float* __restrict__ dec)
{
    int lane = threadIdx.x & 63;
    int wv = __builtin_amdgcn_readfirstlane((int)(threadIdx.x >> 6)); // 0..3
    int di = wv >> 1, dj = wv & 1;
    int cell = blockIdx.x * 64 + lane;          // < 348160 = NINST*32*32
    int inst = cell >> 10, rc2 = cell & 1023;
    int i = rc2 >> 5, j = rc2 & 31;

    const float* xp = X + (size_t)cell * 16;    // HWC row of 16 channels
    float4 x0 = *(const float4*)xp;
    float4 x1 = *(const float4*)(xp + 4);
    float4 x2 = *(const float4*)(xp + 8);
    float4 x3 = *(const float4*)(xp + 12);
    float xk[16] = {x0.x,x0.y,x0.z,x0.w, x1.x,x1.y,x1.z,x1.w,
                    x2.x,x2.y,x2.z,x2.w, x3.x,x3.y,x3.z,x3.w};

    const float* wp = Wt + (3 - (2 * di + dj)) * 48;   // [k][co] 16x3, tap-flipped
    float c0 = bias[0], c1 = bias[1], c2 = bias[2];
    #pragma unroll
    for (int k = 0; k < 16; ++k) {
        c0 = fmaf(xk[k], wp[k * 3 + 0], c0);
        c1 = fmaf(xk[k], wp[k * 3 + 1], c1);
        c2 = fmaf(xk[k], wp[k * 3 + 2], c2);
    }
    c0 = 1.0f / (1.0f + expf(-c0));
    c1 = 1.0f / (1.0f + expf(-c1));
    c2 = 1.0f / (1.0f + expf(-c2));

    int oy = 2 * i + di, ox = 2 * j + dj;
    float* dp = dec + (size_t)inst * 12288 + (size_t)(oy * 64 + ox) * 3;
    dp[0] = c0; dp[1] = c1; dp[2] = c2;
}

// Fused STN bilinear sample + weighted partial composite.
// grid: (64 pixel tiles 16x16, NSPLIT box chunks, 4 batches)
__global__ __launch_bounds__(256) void composite_k(
    const float* __restrict__ dec, const float* __restrict__ wgt,
    const float* __restrict__ sxs, const float* __restrict__ oxs,
    const float* __restrict__ sys, const float* __restrict__ oys,
    const int* __restrict__ binst, const int* __restrict__ rect,
    const int* __restrict__ cidx, const int* __restrict__ cnt,
    float* __restrict__ part)
{
    int b = blockIdx.z, s = blockIdx.y;
    int tx0 = (blockIdx.x & 7) << 4, ty0 = (blockIdx.x >> 3) << 4;
    int lx = threadIdx.x & 15, ly = threadIdx.x >> 4;
    int w = tx0 + lx, h = ty0 + ly;

    int nb = cnt[b];
    int lo = (nb * s) / NSPLIT, hi = (nb * (s + 1)) / NSPLIT;

    float fw = (float)w, fh = (float)h;
    float a0 = 0.f, a1 = 0.f, a2 = 0.f;
    for (int q = lo; q < hi; ++q) {
        int n = cidx[b * NBOX + q];
        int rc = rect[b * NBOX + n];
        int wlo = rc & 255, whi = (rc >> 8) & 255;
        int hlo = (rc >> 16) & 255, hhi = (rc >> 24) & 255;
        if (whi < tx0 || wlo > tx0 + 15 || hhi < ty0 || hlo > ty0 + 15) continue;
        int g = b * NBOX + n;
        float wg = wgt[g];
        float px = fmaf(fw, sxs[g], oxs[g]);
        float py = fmaf(fh, sys[g], oys[g]);
        float x0 = floorf(px), y0 = floorf(py);
        if (x0 < -1.0f || x0 > 63.0f || y0 < -1.0f || y0 > 63.0f) continue;
        float wx = px - x0, wy = py - y0;
        int ix = (int)x0, iy = (int)y0;
        int x0c = max(ix, 0), x1c = min(ix + 1, 63);
        int y0c = max(iy, 0), y1c = min(iy + 1, 63);
        float m00 = (ix >= 0 && iy >= 0) ? 1.f : 0.f;
        float m01 = (ix + 1 <= 63 && iy >= 0) ? 1.f : 0.f;
        float m10 = (ix >= 0 && iy + 1 <= 63) ? 1.f : 0.f;
        float m11 = (ix + 1 <= 63 && iy + 1 <= 63) ? 1.f : 0.f;
        float w00 = (1.f - wy) * (1.f - wx) * m00;
        float w01 = (1.f - wy) * wx * m01;
        float w10 = wy * (1.f - wx) * m10;
        float w11 = wy * wx * m11;
        const float* img = dec + (size_t)binst[g] * 12288;   // (64,64,3) HWC
        int b00 = (y0c * 64 + x0c) * 3, b01 = (y0c * 64 + x1c) * 3;
        int b10 = (y1c * 64 + x0c) * 3, b11 = (y1c * 64 + x1c) * 3;
        a0 += wg * (w00 * img[b00]   + w01 * img[b01]   + w10 * img[b10]   + w11 * img[b11]);
        a1 += wg * (w00 * img[b00+1] + w01 * img[b01+1] + w10 * img[b10+1] + w11 * img[b11+1]);
        a2 += wg * (w00 * img[b00+2] + w01 * img[b01+2] + w10 * img[b10+2] + w11 * img[b11+2]);
    }
    size_t pb = (size_t)(b * NSPLIT + s) * 49152 + (size_t)h * 128 + w;
    part[pb]         = a0;
    part[pb + 16384] = a1;
    part[pb + 32768] = a2;
}

__global__ void reduce_k(const float* __restrict__ part, float* __restrict__ out)
{
    int i = blockIdx.x * 256 + threadIdx.x;   // < 196608
    int b = i / 49152;
    int r = i - b * 49152;
    float v = 0.f;
    #pragma unroll
    for (int s = 0; s < NSPLIT; ++s) v += part[(size_t)(b * NSPLIT + s) * 49152 + r];
    out[i] = v;
}

extern "C" void kernel_launch(void* const* d_in, const int* in_sizes, int n_in,
                              void* d_out, int out_size, void* d_ws, size_t ws_size,
                              hipStream_t stream)
{
    const float* z_what   = (const float*)d_in[0];   // (4,85,64)
    const float* z_where  = (const float*)d_in[1];   // (4,380,4)
    const int*   z_present= (const int*)  d_in[2];   // (4,380,1)
    const float* z_depth  = (const float*)d_in[3];   // (4,85,1)
    const float* W[6]; const float* Bs[6];
    for (int i = 0; i < 6; ++i) {
        W[i]  = (const float*)d_in[4 + 2 * i];
        Bs[i] = (const float*)d_in[5 + 2 * i];
    }

    // workspace (bytes):
    //   A: 0..22,282,240     L0/L2/L4 outs; partials reuse it after L5
    //   B: +16,711,680       L1/L3 outs; decoded HWC3
    //   P: params (8 arrays of 1520 + cnt)
    char* ws = (char*)d_ws;
    float* A    = (float*)ws;
    float* Bbuf = (float*)(ws + 22282240);
    float* P    = (float*)(ws + 38993920);
    float* wgt = P,       *sxs = P + 1520, *oxs = P + 2 * 1520;
    float* sys = P + 3 * 1520, *oys = P + 4 * 1520;
    int* binst = (int*)(P + 5 * 1520);
    int* rect  = (int*)(P + 6 * 1520);
    int* cidx  = (int*)(P + 7 * 1520);
    int* cnt   = (int*)(P + 8 * 1520);
    float* part = A;   // 4*4*3*16384 f32 = 3.15 MB, A is free by composite time

    box_params_k<<<dim3(4), dim3(128), 0, stream>>>(z_where, z_present, z_depth,
        wgt, sxs, oxs, sys, oys, binst, rect, cidx, cnt);

    // layer configs: M, K, coutsh, sinsh
    deconv_gemm_k<4><<<dim3(6, 16),   dim3(256), 0, stream>>>(z_what, W[0], Bs[0], A,    340,    64, 8, 0, 0);
    deconv_gemm_k<2><<<dim3(43, 8),   dim3(256), 0, stream>>>(A,      W[1], Bs[1], Bbuf, 1360,  256, 7, 1, 0);
    deconv_gemm_k<4><<<dim3(85, 4),   dim3(256), 0, stream>>>(Bbuf,   W[2], Bs[2], A,    5440,  128, 6, 2, 0);
    deconv_gemm_k<4><<<dim3(340, 2),  dim3(256), 0, stream>>>(A,      W[3], Bs[3], Bbuf, 21760,  64, 5, 3, 0);
    deconv_gemm_k<4><<<dim3(1360, 1), dim3(256), 0, stream>>>(Bbuf,   W[4], Bs[4], A,    87040,  32, 4, 4, 0);
    deconv_last_k<<<dim3(5440), dim3(256), 0, stream>>>(A, W[5], Bs[5], Bbuf);

    composite_k<<<dim3(64, NSPLIT, 4), dim3(256), 0, stream>>>(Bbuf, wgt, sxs, oxs, sys, oys,
        binst, rect, cidx, cnt, part);
    reduce_k<<<dim3(768), dim3(256), 0, stream>>>(part, (float*)d_out);
}